// Round 4
// baseline (149.480 us; speedup 1.0000x reference)
//
#include <hip/hip_runtime.h>

#define NB 4
#define NC 256
#define NI 32
#define NN 4096
#define NSPLIT 8
#define KVQ (NN / NSPLIT)  // 512

typedef short s4v __attribute__((ext_vector_type(4)));
typedef short s8v __attribute__((ext_vector_type(8)));
typedef float f16v __attribute__((ext_vector_type(16)));
typedef unsigned u4v __attribute__((ext_vector_type(4)));

__device__ __forceinline__ unsigned short f2bf(float f) {
  unsigned u = __builtin_bit_cast(unsigned, f);
  return (unsigned short)((u + 0x7FFFu + ((u >> 16) & 1u)) >> 16);
}

__device__ __forceinline__ float fast_exp2(float x) {  // v_exp_f32 computes 2^x
  float r;
  asm("v_exp_f32 %0, %1" : "=v"(r) : "v"(x));
  return r;
}

// ---------------- Kernel 1: QKV projection ----------------
// grid: 3 proj * 2 ch-half * NB * (NN/64) = 1536 blocks, 256 threads (6 waves/SIMD).
// Each wave: 4 output channels x 64 n. Weights/bias read via wave-uniform scalar
// loads (s_load through K-cache) — no LDS, no vector loads for w.
// K is pre-scaled by log2(e) so attention uses v_exp_f32 (2^x) directly.
__global__ __launch_bounds__(256) void qkv_proj(
    const float* __restrict__ x,
    const float* __restrict__ wq, const float* __restrict__ bq,
    const float* __restrict__ wk, const float* __restrict__ bk,
    const float* __restrict__ wv, const float* __restrict__ bv,
    unsigned short* __restrict__ Qb, unsigned short* __restrict__ Kb,
    unsigned short* __restrict__ Vt) {
  const int tid = threadIdx.x;
  const int ph = blockIdx.x >> 8;        // 0..5 = proj*2 + half
  const int proj = ph >> 1;              // 0=q 1=k 2=v
  const int half = ph & 1;
  const int bt = blockIdx.x & 255;
  const int b = bt >> 6;
  const int n = (bt & 63) * 64 + (tid & 63);
  // wave-uniform channel base, forced into an SGPR so w/bias loads scalarize
  const int obu = __builtin_amdgcn_readfirstlane(half * 16 + (tid >> 6) * 4);

  const float* w;
  const float* bias;
  if (proj == 0) { w = wq; bias = bq; }
  else if (proj == 1) { w = wk; bias = bk; }
  else { w = wv; bias = bv; }
  const float* wp = w + (size_t)obu * NC;

  float acc[4] = {};
  const float* xp = x + ((size_t)b * NC) * NN + n;
#pragma unroll 4
  for (int c0 = 0; c0 < NC; c0 += 4) {
    const float xv0 = xp[(size_t)(c0 + 0) * NN];
    const float xv1 = xp[(size_t)(c0 + 1) * NN];
    const float xv2 = xp[(size_t)(c0 + 2) * NN];
    const float xv3 = xp[(size_t)(c0 + 3) * NN];
#pragma unroll
    for (int e = 0; e < 4; ++e) {
      const float4 w4 = *reinterpret_cast<const float4*>(&wp[e * NC + c0]);  // s_load
      acc[e] += w4.x * xv0 + w4.y * xv1 + w4.z * xv2 + w4.w * xv3;
    }
  }

  if (proj < 2) {
    const float sc = proj ? 1.44269504089f : 1.0f;  // fold log2(e) into K
    s4v pv;
#pragma unroll
    for (int e = 0; e < 4; ++e) pv[e] = (short)f2bf((acc[e] + bias[obu + e]) * sc);
    unsigned short* dst = proj == 0 ? Qb : Kb;
    *reinterpret_cast<s4v*>(&dst[((size_t)b * NN + n) * NI + obu]) = pv;
  } else {
#pragma unroll
    for (int e = 0; e < 4; ++e)
      Vt[((size_t)b * NI + obu + e) * NN + n] = f2bf(acc[e] + bias[obu + e]);
  }
}

// ---------------- Kernel 2: flash attention partial, 32x32 swapped-operand ----------------
// grid: NSPLIT * NB * (NN/128) = 1024 blocks, 256 threads = 4 independent waves.
// Wave owns 32 q-rows. S = mfma32(K, Q) puts a full 32-k slice of S on each lane
// (q = lane&31): softmax denom is per-lane; P->A-frag via cvt_pk + permlane32_swap.
// No LDS, no barriers, no per-tile cross-lane reductions.
__global__ __launch_bounds__(256) void attn_part(
    const unsigned short* __restrict__ Qb, const unsigned short* __restrict__ Kb,
    const unsigned short* __restrict__ Vt,
    unsigned short* __restrict__ Opart, float* __restrict__ Lpart) {
  const int tid = threadIdx.x;
  const int split = blockIdx.x >> 7;
  const int bt = blockIdx.x & 127;
  const int b = bt >> 5;
  const int qw = ((bt & 31) << 7) + ((tid >> 6) << 5);  // wave's 32-q base
  const int lane = tid & 63;
  const int l31 = lane & 31;
  const int hi = lane >> 5;

  // Q B-frags (col = q = lane&31, k = ch = 8*hi+e), contiguous 16B
  const unsigned short* qp = Qb + ((size_t)b * NN + qw + l31) * NI + 8 * hi;
  const s8v qf0 = *reinterpret_cast<const s8v*>(qp);
  const s8v qf1 = *reinterpret_cast<const s8v*>(qp + 16);

  const unsigned short* kp = Kb + ((size_t)b * NN + (size_t)split * KVQ + l31) * NI + 8 * hi;
  const unsigned short* vp = Vt + ((size_t)b * NI + l31) * NN + (size_t)split * KVQ + 8 * hi;

  const f16v zero16 = {};
  f16v oacc = {};
  float lsum = 0.f;

#pragma unroll 4
  for (int kv = 0; kv < KVQ; kv += 32) {
    // K A-frags (row = kv = lane&31, k = ch = 8*hi+e)
    const s8v kf0 = *reinterpret_cast<const s8v*>(kp + (size_t)kv * NI);
    const s8v kf1 = *reinterpret_cast<const s8v*>(kp + (size_t)kv * NI + 16);
    // V B-frags (col = c = lane&31, k = kv = 8*hi+e), from Vt[c][n]
    const s8v vf0 = *reinterpret_cast<const s8v*>(vp + kv);
    const s8v vf1 = *reinterpret_cast<const s8v*>(vp + kv + 16);

    // S[kv'][q]: lane holds kv' = (r&3)+8*(r>>2)+4*hi for its q = lane&31
    f16v S = __builtin_amdgcn_mfma_f32_32x32x16_bf16(kf0, qf0, zero16, 0, 0, 0);
    S = __builtin_amdgcn_mfma_f32_32x32x16_bf16(kf1, qf1, S, 0, 0, 0);

    float p[16];
#pragma unroll
    for (int r = 0; r < 16; ++r) p[r] = fast_exp2(S[r]);
    // tree-sum into per-lane denominator
    float t0 = (p[0] + p[1]) + (p[2] + p[3]);
    float t1 = (p[4] + p[5]) + (p[6] + p[7]);
    float t2 = (p[8] + p[9]) + (p[10] + p[11]);
    float t3 = (p[12] + p[13]) + (p[14] + p[15]);
    lsum += (t0 + t1) + (t2 + t3);

    // pack to bf16 pairs along kv' (pairs r=2j,2j+1 are kv-adjacent)
    unsigned d[8];
#pragma unroll
    for (int j = 0; j < 8; ++j)
      asm("v_cvt_pk_bf16_f32 %0, %1, %2" : "=v"(d[j]) : "v"(p[2 * j]), "v"(p[2 * j + 1]));
    // half-exchange: after swaps, {d0..d3} = A-frag kv 0..15, {d4..d7} = kv 16..31
    asm("v_permlane32_swap_b32 %0, %1" : "+v"(d[0]), "+v"(d[2]));
    asm("v_permlane32_swap_b32 %0, %1" : "+v"(d[1]), "+v"(d[3]));
    asm("v_permlane32_swap_b32 %0, %1" : "+v"(d[4]), "+v"(d[6]));
    asm("v_permlane32_swap_b32 %0, %1" : "+v"(d[5]), "+v"(d[7]));

    const u4v a0 = {d[0], d[1], d[2], d[3]};
    const u4v a1 = {d[4], d[5], d[6], d[7]};
    const s8v pa0 = __builtin_bit_cast(s8v, a0);
    const s8v pa1 = __builtin_bit_cast(s8v, a1);

    oacc = __builtin_amdgcn_mfma_f32_32x32x16_bf16(pa0, vf0, oacc, 0, 0, 0);
    oacc = __builtin_amdgcn_mfma_f32_32x32x16_bf16(pa1, vf1, oacc, 0, 0, 0);
  }

  lsum += __shfl_xor(lsum, 32, 64);  // partner lane holds the other 16 kv

  // Opart[split][b][n][32] bf16: per reg, lanes cover 2 q-rows x 32 c (coalesced)
  unsigned short* op = Opart + (((size_t)split * NB + b) * NN + qw) * NI + l31;
#pragma unroll
  for (int r = 0; r < 16; ++r) {
    const int qr = (r & 3) + 8 * (r >> 2) + 4 * hi;
    op[(size_t)qr * NI] = f2bf(oacc[r]);
  }
  if (hi == 0)
    Lpart[((size_t)split * NB + b) * NN + qw + l31] = lsum;
}

// ---------------- Kernel 3: combine partials + output projection ----------------
// grid: 8 co-groups * NB * (NN/64) = 2048 blocks, 256 threads (8 waves/SIMD).
__global__ __launch_bounds__(256) void combine_proj(
    const unsigned short* __restrict__ Opart, const float* __restrict__ Lpart,
    const float* __restrict__ wo, const float* __restrict__ bo,
    float* __restrict__ out) {
  __shared__ __align__(16) float o_lds[NI][65];
  __shared__ float linv[64];
  const int tid = threadIdx.x;
  const int g2 = blockIdx.x >> 8;        // co-group 0..7 (32 channels each)
  const int bt = blockIdx.x & 255;
  const int b = bt >> 6;
  const int q0 = (bt & 63) * 64;

  {  // stage: thread t = (q = t>>2, c-chunk cg = t&3); fully coalesced s8v loads
    const int qs = tid >> 2, cg = tid & 3;
    float s[8] = {};
#pragma unroll
    for (int sp = 0; sp < NSPLIT; ++sp) {
      const s8v v = *reinterpret_cast<const s8v*>(
          &Opart[(((size_t)sp * NB + b) * NN + q0 + qs) * NI + cg * 8]);
#pragma unroll
      for (int e = 0; e < 8; ++e) {
        const unsigned u = (unsigned)(unsigned short)v[e];
        s[e] += __builtin_bit_cast(float, u << 16);
      }
    }
#pragma unroll
    for (int e = 0; e < 8; ++e) o_lds[cg * 8 + e][qs] = s[e];
  }
  if (tid < 64) {
    float l = 0.f;
#pragma unroll
    for (int sp = 0; sp < NSPLIT; ++sp)
      l += Lpart[((size_t)sp * NB + b) * NN + q0 + tid];
    linv[tid] = 1.0f / l;
  }
  __syncthreads();

  const int q = tid & 63;
  const float il = linv[q];
  float xv[NI];
#pragma unroll
  for (int c = 0; c < NI; ++c) xv[c] = o_lds[c][q] * il;

  float* op2 = out + ((size_t)b * NC) * NN + q0 + q;
  const int co0 = g2 * 32 + (tid >> 6) * 8;  // 8 channels per wave
#pragma unroll
  for (int cc = 0; cc < 8; ++cc) {
    const int co = co0 + cc;
    float a = bo[co];
#pragma unroll
    for (int c4 = 0; c4 < 8; ++c4) {
      const float4 w4 = *reinterpret_cast<const float4*>(&wo[co * NI + c4 * 4]);
      a += w4.x * xv[c4 * 4] + w4.y * xv[c4 * 4 + 1] +
           w4.z * xv[c4 * 4 + 2] + w4.w * xv[c4 * 4 + 3];
    }
    op2[(size_t)co * NN] = a;
  }
}

extern "C" void kernel_launch(void* const* d_in, const int* in_sizes, int n_in,
                              void* d_out, int out_size, void* d_ws, size_t ws_size,
                              hipStream_t stream) {
  const float* x  = (const float*)d_in[0];
  const float* wq = (const float*)d_in[1];
  const float* bq = (const float*)d_in[2];
  const float* wk = (const float*)d_in[3];
  const float* bk = (const float*)d_in[4];
  const float* wv = (const float*)d_in[5];
  const float* bv = (const float*)d_in[6];
  const float* wo = (const float*)d_in[7];
  const float* bo = (const float*)d_in[8];
  float* out = (float*)d_out;

  unsigned short* Qb = (unsigned short*)d_ws;                 // [NB][NN][NI] bf16 (1 MB)
  unsigned short* Kb = Qb + (size_t)NB * NN * NI;             // 1 MB (pre-scaled by log2e)
  unsigned short* Vt = Kb + (size_t)NB * NN * NI;             // [NB][NI][NN] 1 MB
  unsigned short* Opart = Vt + (size_t)NB * NI * NN;          // [8][NB][NN][NI] bf16 (8 MB)
  float* Lpart = (float*)(Opart + (size_t)NSPLIT * NB * NN * NI);  // [8][NB][NN] (512 KB)

  qkv_proj<<<3 * 2 * NB * (NN / 64), 256, 0, stream>>>(x, wq, bq, wk, bk, wv, bv, Qb, Kb, Vt);
  attn_part<<<NSPLIT * NB * (NN / 128), 256, 0, stream>>>(Qb, Kb, Vt, Opart, Lpart);
  combine_proj<<<8 * NB * (NN / 64), 256, 0, stream>>>(Opart, Lpart, wo, bo, out);
}

// Round 5
// 129.296 us; speedup vs baseline: 1.1561x; 1.1561x over previous
//
#include <hip/hip_runtime.h>

#define NB 4
#define NC 256
#define NI 32
#define NN 4096
#define NSPLIT 8
#define KVQ (NN / NSPLIT)  // 512

typedef short s4v __attribute__((ext_vector_type(4)));
typedef short s8v __attribute__((ext_vector_type(8)));
typedef float f16v __attribute__((ext_vector_type(16)));
typedef unsigned u4v __attribute__((ext_vector_type(4)));

__device__ __forceinline__ unsigned short f2bf(float f) {
  unsigned u = __builtin_bit_cast(unsigned, f);
  return (unsigned short)((u + 0x7FFFu + ((u >> 16) & 1u)) >> 16);
}

__device__ __forceinline__ float fast_exp2(float x) {  // v_exp_f32 computes 2^x
  float r;
  asm("v_exp_f32 %0, %1" : "=v"(r) : "v"(x));
  return r;
}

__device__ __forceinline__ unsigned cvtpk(float lo, float hi) {
  unsigned r;
  asm("v_cvt_pk_bf16_f32 %0, %1, %2" : "=v"(r) : "v"(lo), "v"(hi));
  return r;
}

// ---------------- Kernel 1: fused QKV projection via MFMA ----------------
// grid: NB * (NN/32) = 512 blocks, 256 threads = 4 waves (2 blocks/CU).
// Block covers 32 n-columns, full K=256; wave w covers k in [64w, 64w+64).
// x loaded ONCE (fp32->bf16 in-register), B-frags shared by Q/K/V MFMA chains.
// fp32 partials reduced through padded LDS; bias + log2(e) K-fold in epilogue.
// Outputs: Qb[b][n][32], Kb[b][n][32] (log2e-scaled), V3[b][n/32][c][n%32].
__global__ __launch_bounds__(256) void qkv_mfma(
    const float* __restrict__ x,
    const float* __restrict__ wq, const float* __restrict__ bq,
    const float* __restrict__ wk, const float* __restrict__ bk,
    const float* __restrict__ wv, const float* __restrict__ bv,
    unsigned short* __restrict__ Qb, unsigned short* __restrict__ Kb,
    unsigned short* __restrict__ V3) {
  __shared__ float part[4][3][32][33];  // 50.7 KB, padded: conflict-free reduce
  const int tid = threadIdx.x;
  const int w = tid >> 6;
  const int lane = tid & 63;
  const int l31 = lane & 31;
  const int hi = lane >> 5;
  const int b = blockIdx.x >> 7;
  const int nb = blockIdx.x & 127;
  const int n0 = nb * 32;

  const float* xb = x + (size_t)b * NC * NN + n0 + l31;

  f16v accQ = {}, accK = {}, accV = {};
#pragma unroll
  for (int j = 0; j < 4; ++j) {
    const int c0 = w * 64 + j * 16;
    // x B-frag: lane needs x[c0+8hi+e][n0+l31], e=0..7 (8 coalesced dword loads)
    float xe[8];
#pragma unroll
    for (int e = 0; e < 8; ++e) xe[e] = xb[(size_t)(c0 + 8 * hi + e) * NN];
    u4v xp;
#pragma unroll
    for (int e2 = 0; e2 < 4; ++e2) xp[e2] = cvtpk(xe[2 * e2], xe[2 * e2 + 1]);
    const s8v xf = __builtin_bit_cast(s8v, xp);

    // W A-frags: lane needs W[l31][c0+8hi+e] (8 consecutive floats)
    const int wo_ = l31 * NC + c0 + 8 * hi;
    {
      const float4 a = *reinterpret_cast<const float4*>(&wq[wo_]);
      const float4 c = *reinterpret_cast<const float4*>(&wq[wo_ + 4]);
      u4v wp = {cvtpk(a.x, a.y), cvtpk(a.z, a.w), cvtpk(c.x, c.y), cvtpk(c.z, c.w)};
      accQ = __builtin_amdgcn_mfma_f32_32x32x16_bf16(__builtin_bit_cast(s8v, wp), xf, accQ, 0, 0, 0);
    }
    {
      const float4 a = *reinterpret_cast<const float4*>(&wk[wo_]);
      const float4 c = *reinterpret_cast<const float4*>(&wk[wo_ + 4]);
      u4v wp = {cvtpk(a.x, a.y), cvtpk(a.z, a.w), cvtpk(c.x, c.y), cvtpk(c.z, c.w)};
      accK = __builtin_amdgcn_mfma_f32_32x32x16_bf16(__builtin_bit_cast(s8v, wp), xf, accK, 0, 0, 0);
    }
    {
      const float4 a = *reinterpret_cast<const float4*>(&wv[wo_]);
      const float4 c = *reinterpret_cast<const float4*>(&wv[wo_ + 4]);
      u4v wp = {cvtpk(a.x, a.y), cvtpk(a.z, a.w), cvtpk(c.x, c.y), cvtpk(c.z, c.w)};
      accV = __builtin_amdgcn_mfma_f32_32x32x16_bf16(__builtin_bit_cast(s8v, wp), xf, accV, 0, 0, 0);
    }
  }

  // write partials: D row = (r&3)+8*(r>>2)+4*hi, col = l31
#pragma unroll
  for (int r = 0; r < 16; ++r) {
    const int row = (r & 3) + 8 * (r >> 2) + 4 * hi;
    part[w][0][row][l31] = accQ[r];
    part[w][1][row][l31] = accK[r];
    part[w][2][row][l31] = accV[r];
  }
  __syncthreads();

  // ---- reduce + store ----
  // Q/K: thread t -> n = t>>3, ch-group cg = (t&7)*4 (8 threads = one 64B row)
  {
    const int n_l = tid >> 3;
    const int cg = (tid & 7) * 4;
    float sq[4] = {}, sk[4] = {};
#pragma unroll
    for (int ww = 0; ww < 4; ++ww)
#pragma unroll
      for (int jj = 0; jj < 4; ++jj) {
        sq[jj] += part[ww][0][cg + jj][n_l];
        sk[jj] += part[ww][1][cg + jj][n_l];
      }
    s4v qv, kv;
#pragma unroll
    for (int jj = 0; jj < 4; ++jj) {
      qv[jj] = (short)f2bf(sq[jj] + bq[cg + jj]);
      kv[jj] = (short)f2bf((sk[jj] + bk[cg + jj]) * 1.44269504089f);
    }
    *reinterpret_cast<s4v*>(&Qb[((size_t)b * NN + n0 + n_l) * NI + cg]) = qv;
    *reinterpret_cast<s4v*>(&Kb[((size_t)b * NN + n0 + n_l) * NI + cg]) = kv;
  }
  // V: thread t -> n = t&31, c = (t>>5)*4 + i ; V3[b][nb][c][n]
  {
    const int n_l = tid & 31;
    const int cb = (tid >> 5) * 4;
    unsigned short* vdst = V3 + (((size_t)b * 128 + nb) * 32) * 32;
#pragma unroll
    for (int i = 0; i < 4; ++i) {
      const int c = cb + i;
      float s = part[0][2][c][n_l] + part[1][2][c][n_l] +
                part[2][2][c][n_l] + part[3][2][c][n_l];
      vdst[(size_t)c * 32 + n_l] = f2bf(s + bv[c]);
    }
  }
}

// ---------------- Kernel 2: flash attention partial, 32x32 swapped-operand ----------------
// grid: NSPLIT * NB * (NN/128) = 1024 blocks, 256 threads = 4 independent waves.
// Wave owns 32 q-rows. S = mfma32(K, Q): softmax denom per-lane; P->A-frag via
// cvt_pk + permlane32_swap. V read from tiled V3[b][n/32][c][n%32] (64B lane
// stride vs 8KB with [c][n] layout -> 4x fewer fetch segments).
__global__ __launch_bounds__(256) void attn_part(
    const unsigned short* __restrict__ Qb, const unsigned short* __restrict__ Kb,
    const unsigned short* __restrict__ V3,
    unsigned short* __restrict__ Opart, float* __restrict__ Lpart) {
  const int tid = threadIdx.x;
  const int split = blockIdx.x >> 7;
  const int bt = blockIdx.x & 127;
  const int b = bt >> 5;
  const int qw = ((bt & 31) << 7) + ((tid >> 6) << 5);  // wave's 32-q base
  const int lane = tid & 63;
  const int l31 = lane & 31;
  const int hi = lane >> 5;

  const unsigned short* qp = Qb + ((size_t)b * NN + qw + l31) * NI + 8 * hi;
  const s8v qf0 = *reinterpret_cast<const s8v*>(qp);
  const s8v qf1 = *reinterpret_cast<const s8v*>(qp + 16);

  const unsigned short* kp = Kb + ((size_t)b * NN + (size_t)split * KVQ + l31) * NI + 8 * hi;
  // V3 frag base: row = c = l31 within the kv 32-block
  const unsigned short* vp =
      V3 + (((size_t)b * 128 + (split * KVQ) / 32) * 32 + l31) * 32 + 8 * hi;

  const f16v zero16 = {};
  f16v oacc = {};
  float lsum = 0.f;

#pragma unroll 4
  for (int kv = 0; kv < KVQ; kv += 32) {
    const s8v kf0 = *reinterpret_cast<const s8v*>(kp + (size_t)kv * NI);
    const s8v kf1 = *reinterpret_cast<const s8v*>(kp + (size_t)kv * NI + 16);
    // V B-frags from tiled layout: vf0 = V^T[kv..kv+15][c], vf1 = +16
    const s8v vf0 = *reinterpret_cast<const s8v*>(vp + (size_t)kv * 32);
    const s8v vf1 = *reinterpret_cast<const s8v*>(vp + (size_t)kv * 32 + 16);

    f16v S = __builtin_amdgcn_mfma_f32_32x32x16_bf16(kf0, qf0, zero16, 0, 0, 0);
    S = __builtin_amdgcn_mfma_f32_32x32x16_bf16(kf1, qf1, S, 0, 0, 0);

    float p[16];
#pragma unroll
    for (int r = 0; r < 16; ++r) p[r] = fast_exp2(S[r]);
    float t0 = (p[0] + p[1]) + (p[2] + p[3]);
    float t1 = (p[4] + p[5]) + (p[6] + p[7]);
    float t2 = (p[8] + p[9]) + (p[10] + p[11]);
    float t3 = (p[12] + p[13]) + (p[14] + p[15]);
    lsum += (t0 + t1) + (t2 + t3);

    unsigned d[8];
#pragma unroll
    for (int j = 0; j < 8; ++j) d[j] = cvtpk(p[2 * j], p[2 * j + 1]);
    asm("v_permlane32_swap_b32 %0, %1" : "+v"(d[0]), "+v"(d[2]));
    asm("v_permlane32_swap_b32 %0, %1" : "+v"(d[1]), "+v"(d[3]));
    asm("v_permlane32_swap_b32 %0, %1" : "+v"(d[4]), "+v"(d[6]));
    asm("v_permlane32_swap_b32 %0, %1" : "+v"(d[5]), "+v"(d[7]));

    const u4v a0 = {d[0], d[1], d[2], d[3]};
    const u4v a1 = {d[4], d[5], d[6], d[7]};
    oacc = __builtin_amdgcn_mfma_f32_32x32x16_bf16(__builtin_bit_cast(s8v, a0), vf0, oacc, 0, 0, 0);
    oacc = __builtin_amdgcn_mfma_f32_32x32x16_bf16(__builtin_bit_cast(s8v, a1), vf1, oacc, 0, 0, 0);
  }

  lsum += __shfl_xor(lsum, 32, 64);

  unsigned short* op = Opart + (((size_t)split * NB + b) * NN + qw) * NI + l31;
#pragma unroll
  for (int r = 0; r < 16; ++r) {
    const int qr = (r & 3) + 8 * (r >> 2) + 4 * hi;
    op[(size_t)qr * NI] = f2bf(oacc[r]);
  }
  if (hi == 0)
    Lpart[((size_t)split * NB + b) * NN + qw + l31] = lsum;
}

// ---------------- Kernel 3: combine partials + output projection ----------------
// grid: 8 co-groups * NB * (NN/64) = 2048 blocks, 256 threads.
__global__ __launch_bounds__(256) void combine_proj(
    const unsigned short* __restrict__ Opart, const float* __restrict__ Lpart,
    const float* __restrict__ wo, const float* __restrict__ bo,
    float* __restrict__ out) {
  __shared__ __align__(16) float o_lds[NI][65];
  __shared__ float linv[64];
  const int tid = threadIdx.x;
  const int g2 = blockIdx.x >> 8;        // co-group 0..7 (32 channels each)
  const int bt = blockIdx.x & 255;
  const int b = bt >> 6;
  const int q0 = (bt & 63) * 64;

  {
    const int qs = tid >> 2, cg = tid & 3;
    float s[8] = {};
#pragma unroll
    for (int sp = 0; sp < NSPLIT; ++sp) {
      const s8v v = *reinterpret_cast<const s8v*>(
          &Opart[(((size_t)sp * NB + b) * NN + q0 + qs) * NI + cg * 8]);
#pragma unroll
      for (int e = 0; e < 8; ++e) {
        const unsigned u = (unsigned)(unsigned short)v[e];
        s[e] += __builtin_bit_cast(float, u << 16);
      }
    }
#pragma unroll
    for (int e = 0; e < 8; ++e) o_lds[cg * 8 + e][qs] = s[e];
  }
  if (tid < 64) {
    float l = 0.f;
#pragma unroll
    for (int sp = 0; sp < NSPLIT; ++sp)
      l += Lpart[((size_t)sp * NB + b) * NN + q0 + tid];
    linv[tid] = 1.0f / l;
  }
  __syncthreads();

  const int q = tid & 63;
  const float il = linv[q];
  float xv[NI];
#pragma unroll
  for (int c = 0; c < NI; ++c) xv[c] = o_lds[c][q] * il;

  float* op2 = out + ((size_t)b * NC) * NN + q0 + q;
  const int co0 = g2 * 32 + (tid >> 6) * 8;
#pragma unroll
  for (int cc = 0; cc < 8; ++cc) {
    const int co = co0 + cc;
    float a = bo[co];
#pragma unroll
    for (int c4 = 0; c4 < 8; ++c4) {
      const float4 w4 = *reinterpret_cast<const float4*>(&wo[co * NI + c4 * 4]);
      a += w4.x * xv[c4 * 4] + w4.y * xv[c4 * 4 + 1] +
           w4.z * xv[c4 * 4 + 2] + w4.w * xv[c4 * 4 + 3];
    }
    op2[(size_t)co * NN] = a;
  }
}

extern "C" void kernel_launch(void* const* d_in, const int* in_sizes, int n_in,
                              void* d_out, int out_size, void* d_ws, size_t ws_size,
                              hipStream_t stream) {
  const float* x  = (const float*)d_in[0];
  const float* wq = (const float*)d_in[1];
  const float* bq = (const float*)d_in[2];
  const float* wk = (const float*)d_in[3];
  const float* bk = (const float*)d_in[4];
  const float* wv = (const float*)d_in[5];
  const float* bv = (const float*)d_in[6];
  const float* wo = (const float*)d_in[7];
  const float* bo = (const float*)d_in[8];
  float* out = (float*)d_out;

  unsigned short* Qb = (unsigned short*)d_ws;                 // [NB][NN][NI] bf16 (1 MB)
  unsigned short* Kb = Qb + (size_t)NB * NN * NI;             // 1 MB (pre-scaled by log2e)
  unsigned short* V3 = Kb + (size_t)NB * NN * NI;             // [NB][128][32][32] 1 MB
  unsigned short* Opart = V3 + (size_t)NB * NN * NI;          // [8][NB][NN][NI] bf16 (8 MB)
  float* Lpart = (float*)(Opart + (size_t)NSPLIT * NB * NN * NI);  // [8][NB][NN] (512 KB)

  qkv_mfma<<<NB * (NN / 32), 256, 0, stream>>>(x, wq, bq, wk, bk, wv, bv, Qb, Kb, V3);
  attn_part<<<NSPLIT * NB * (NN / 128), 256, 0, stream>>>(Qb, Kb, V3, Opart, Lpart);
  combine_proj<<<8 * NB * (NN / 64), 256, 0, stream>>>(Opart, Lpart, wo, bo, out);
}